// Round 2
// baseline (182.407 us; speedup 1.0000x reference)
//
#include <hip/hip_runtime.h>

#define N_NODES 20000
#define HID     256
#define DEG     32
#define TOPK    16
#define NRB     313      // ceil(20000/64) row-blocks of 64

typedef __attribute__((ext_vector_type(8))) short short8;
typedef __attribute__((ext_vector_type(4))) float f32x4;
typedef __attribute__((ext_vector_type(2))) _Float16 half2_t;

__device__ inline unsigned short f2bf(float f) {
    unsigned u = __float_as_uint(f);
    unsigned r = (u + 0x7FFFu + ((u >> 16) & 1u)) >> 16;  // RNE
    return (unsigned short)r;
}
__device__ inline float bf_lo(unsigned u) { return __uint_as_float(u << 16); }
__device__ inline float bf_hi(unsigned u) { return __uint_as_float(u & 0xFFFF0000u); }

__device__ inline unsigned short f2h(float f) {
    _Float16 h = (_Float16)f;               // v_cvt_f16_f32 (RNE)
    return __builtin_bit_cast(unsigned short, h);
}
__device__ inline half2_t u2h2(unsigned u) { return __builtin_bit_cast(half2_t, u); }

__device__ inline ushort4 cvt4(float4 f) {
    ushort4 o;
    o.x = f2bf(f.x); o.y = f2bf(f.y); o.z = f2bf(f.z); o.w = f2bf(f.w);
    return o;
}

// static xor-lane exchange within 32-lane groups via ds_swizzle (no vaddr).
#define SWZ_X1  0x041F
#define SWZ_X2  0x081F
#define SWZ_X4  0x101F
#define SWZ_X8  0x201F
#define SWZ_X16 0x401F
template<int IMM>
__device__ __forceinline__ float swz(float x) {
    return __uint_as_float((unsigned)__builtin_amdgcn_ds_swizzle(
        (int)__float_as_uint(x), IMM));
}

// ---------------------------------------------------------------------------
// Weight-stationary GEMM core.
// Ws: 128 cols x 256 k, bf16, XOR-swizzled (byte ^= (row&7)<<4) -> conflict-
// free ds_read_b128 column-slice reads with NO pad (64KB exact).
// As: two 64x64 bf16 chunk buffers (8KB each), same swizzle, reg-staged.
// Total LDS = 80KB -> exactly 2 blocks/CU (8 waves/CU).
// ---------------------------------------------------------------------------
__device__ __forceinline__ unsigned swzA(int row, int colByte) {
    return ((unsigned)(row * 128 + colByte)) ^ (unsigned)((row & 7) << 4);
}
__device__ __forceinline__ unsigned swzW(int row, int colByte) {
    return ((unsigned)(row * 512 + colByte)) ^ (unsigned)((row & 7) << 4);
}

__device__ __forceinline__ void stageA(
    const unsigned short* __restrict__ A, unsigned short* Asb,
    int rowbase, int k0, int M, int t)
{
    #pragma unroll
    for (int c = 0; c < 2; ++c) {
        int ci  = t + 256 * c;     // 0..511
        int row = ci >> 3;         // 8 x 16B chunks per 64-col row
        int grow = rowbase + row;
        uint4 v = make_uint4(0u, 0u, 0u, 0u);
        if (grow < M)
            v = *(const uint4*)(A + (size_t)grow * 256 + k0 * 64 + (ci & 7) * 8);
        *(uint4*)((char*)Asb + swzA(row, (ci & 7) * 16)) = v;
    }
}

// one 64-row x 128-col output block, K=256, W resident in LDS
__device__ __forceinline__ void ws_rowblock(
    const unsigned short* __restrict__ A,
    unsigned short* Ws, unsigned short* As0, unsigned short* As1,
    int rowbase, int M, f32x4 acc[2][4], int t)
{
    const int lane = t & 63;
    const int wave = t >> 6;
    const int wm   = (wave & 1) * 32;
    const int wn   = (wave >> 1) * 64;
    const int lm   = lane & 15;
    const int q8   = (lane >> 4) * 8;

    stageA(A, As0, rowbase, 0, M, t);
    __syncthreads();                       // also covers W preload visibility

    unsigned short* bufs[2] = {As0, As1};
    #pragma unroll
    for (int k0 = 0; k0 < 4; ++k0) {
        unsigned short* cur = bufs[k0 & 1];
        if (k0 < 3) stageA(A, bufs[(k0 + 1) & 1], rowbase, k0 + 1, M, t);
        #pragma unroll
        for (int kk = 0; kk < 64; kk += 32) {
            short8 af[2], bfr[4];
            #pragma unroll
            for (int i = 0; i < 2; ++i)
                af[i] = *(const short8*)((const char*)cur
                         + swzA(wm + i * 16 + lm, (kk + q8) * 2));
            #pragma unroll
            for (int j = 0; j < 4; ++j)
                bfr[j] = *(const short8*)((const char*)Ws
                         + swzW(wn + j * 16 + lm, (k0 * 64 + kk + q8) * 2));
            #pragma unroll
            for (int i = 0; i < 2; ++i)
                #pragma unroll
                for (int j = 0; j < 4; ++j)
                    acc[i][j] = __builtin_amdgcn_mfma_f32_16x16x32_bf16(
                        bfr[j], af[i], acc[i][j], 0, 0, 0);   // swapped operands
        }
        __syncthreads();
    }
}

// ---------------------------------------------------------------------------
// Dispatch 0: prep — h fp32->bf16 (once), Wq/Wk/Wv/Wo fp32->bf16 (once, into
// one contiguous Wb buffer), top-16 edge-weight mask + normalize.
// ---------------------------------------------------------------------------
__global__ __launch_bounds__(256) void prep(
    const float* __restrict__ h,
    const float* __restrict__ Wq, const float* __restrict__ Wk,
    const float* __restrict__ Wv, const float* __restrict__ Wo,
    const float* __restrict__ ew,
    unsigned short* __restrict__ hb, unsigned short* __restrict__ Wb,
    float* __restrict__ wgt)
{
    const int id = blockIdx.x;
    const int t  = threadIdx.x;

    if (id < 2500) {                      // ---- h convert ----
        size_t i = ((size_t)id * 256 + t) * 8;
        float4 f0 = *(const float4*)(h + i);
        float4 f1 = *(const float4*)(h + i + 4);
        *(ushort4*)(hb + i)     = cvt4(f0);
        *(ushort4*)(hb + i + 4) = cvt4(f1);
        return;
    }
    if (id < 2628) {                      // ---- W convert ----
        int e = ((id - 2500) * 256 + t) * 8;     // 0..262136
        const float* W = (e < 65536) ? Wq : (e < 131072) ? Wk
                       : (e < 196608) ? Wv : Wo;
        int off = e & 65535;
        float4 f0 = *(const float4*)(W + off);
        float4 f1 = *(const float4*)(W + off + 4);
        *(ushort4*)(Wb + e)     = cvt4(f0);
        *(ushort4*)(Wb + e + 4) = cvt4(f1);
        return;
    }
    // ---- topk ----
    int n = (id - 2628) * 8 + (t >> 5);
    int lane = t & 31;
    float my = ew[n * 32 + lane];
    int cnt = 0;
    #pragma unroll
    for (int j = 0; j < 32; ++j) {
        float o = __shfl(my, j, 32);
        cnt += (o > my || (o == my && j < lane)) ? 1 : 0;
    }
    float w = (cnt < TOPK) ? my : 0.0f;
    float s = w;
    #pragma unroll
    for (int off = 16; off; off >>= 1) s += __shfl_xor(s, off, 32);
    wgt[n * 32 + lane] = w / (s + 1e-5f);
}

// ---------------------------------------------------------------------------
// Dispatch 1: q/k/v projections, weight-stationary persistent blocks.
// Grid 528 = 8 xcd x 66: g = xcd + 8*(rest/6) in 0..87 (row-group),
// v = rest%6 -> (z,by). The 6 variant blocks of a group share an XCD ->
// each A row-block is HBM-read once, L2-served 5x. Each block loads its
// 128x256 W half into LDS ONCE, then loops rb = g, g+88, ... (<=4 blocks).
// ---------------------------------------------------------------------------
__global__ __launch_bounds__(256) void gemm_qkv(
    const unsigned short* __restrict__ A, const unsigned short* __restrict__ Wb,
    const float* __restrict__ bq, const float* __restrict__ bk,
    const float* __restrict__ bv,
    unsigned short* __restrict__ Cq, unsigned short* __restrict__ kvo, int M)
{
    __shared__ unsigned short Ws[128 * 256];
    __shared__ unsigned short As[2][64 * 64];

    const int id   = blockIdx.x;
    const int t    = threadIdx.x;
    const int xcd  = id & 7;
    const int rest = id >> 3;             // 0..65
    const int g    = xcd + 8 * (rest / 6);   // 0..87
    const int v    = rest % 6;
    const int z    = v >> 1;
    const int by   = v & 1;

    const unsigned short* Wsrc = Wb + z * 65536 + by * (128 * 256);
    const float* bias = (z == 0) ? bq : (z == 1) ? bk : bv;

    // W preload: 4096 x 16B chunks, 16/thread (visibility via ws_rowblock sync)
    #pragma unroll
    for (int c = 0; c < 16; ++c) {
        int ci  = t + 256 * c;
        int row = ci >> 5;                // 32 chunks per 256-col row
        uint4 w = *(const uint4*)(Wsrc + (size_t)row * 256 + (ci & 31) * 8);
        *(uint4*)((char*)Ws + swzW(row, (ci & 31) * 16)) = w;
    }

    const int lane = t & 63;
    const int wave = t >> 6;
    const int wm   = (wave & 1) * 32;
    const int wn   = (wave >> 1) * 64;
    const int lm   = lane & 15;
    const int lq   = lane >> 4;

    for (int rb = g; rb < NRB; rb += 88) {
        f32x4 acc[2][4];
        #pragma unroll
        for (int i = 0; i < 2; ++i)
            #pragma unroll
            for (int j = 0; j < 4; ++j)
                acc[i][j] = (f32x4){0.f, 0.f, 0.f, 0.f};

        ws_rowblock(A, Ws, As[0], As[1], rb * 64, M, acc, t);

        #pragma unroll
        for (int i = 0; i < 2; ++i) {
            int node = rb * 64 + wm + i * 16 + lm;
            if (node >= M) continue;
            #pragma unroll
            for (int j = 0; j < 4; ++j) {
                int col0 = by * 128 + wn + j * 16 + lq * 4;   // 4 consecutive cols
                float4 b4 = *(const float4*)(bias + col0);
                float x0 = acc[i][j][0] + b4.x;
                float x1 = acc[i][j][1] + b4.y;
                float x2 = acc[i][j][2] + b4.z;
                float x3 = acc[i][j][3] + b4.w;
                int hh = col0 >> 5, cc = col0 & 31;
                if (z == 0) {
                    ushort4 o; o.x = f2h(x0); o.y = f2h(x1); o.z = f2h(x2); o.w = f2h(x3);
                    *(ushort4*)(Cq + (size_t)hh * ((size_t)N_NODES * 32)
                                   + (size_t)node * 32 + cc) = o;
                } else if (z == 1) {
                    ushort4 o; o.x = f2h(x0); o.y = f2h(x1); o.z = f2h(x2); o.w = f2h(x3);
                    *(ushort4*)(kvo + (size_t)hh * ((size_t)N_NODES * 64)
                                   + (size_t)node * 64 + (cc >> 2) * 8) = o;
                } else {
                    ushort4 o; o.x = f2bf(x0); o.y = f2bf(x1); o.z = f2bf(x2); o.w = f2bf(x3);
                    *(ushort4*)(kvo + (size_t)hh * ((size_t)N_NODES * 64)
                                   + (size_t)node * 64 + (cc >> 2) * 8 + 4) = o;
                }
            }
        }
    }
}

// ---------------------------------------------------------------------------
// Dispatch 3: o-projection, same weight-stationary structure. Grid 256:
// g = xcd + 8*(rest>>1) in 0..127, ch = rest&1; rb = g, g+128, g+256.
// fp32 out + fused leaky-relu.
// ---------------------------------------------------------------------------
__global__ __launch_bounds__(256) void gemm_out(
    const unsigned short* __restrict__ A, const unsigned short* __restrict__ W,
    const float* __restrict__ bias, float* __restrict__ out, int M)
{
    __shared__ unsigned short Ws[128 * 256];
    __shared__ unsigned short As[2][64 * 64];

    const int id   = blockIdx.x;
    const int t    = threadIdx.x;
    const int xcd  = id & 7;
    const int rest = id >> 3;             // 0..31
    const int g    = xcd + 8 * (rest >> 1);  // 0..127
    const int ch   = rest & 1;

    const unsigned short* Wsrc = W + ch * (128 * 256);

    #pragma unroll
    for (int c = 0; c < 16; ++c) {
        int ci  = t + 256 * c;
        int row = ci >> 5;
        uint4 w = *(const uint4*)(Wsrc + (size_t)row * 256 + (ci & 31) * 8);
        *(uint4*)((char*)Ws + swzW(row, (ci & 31) * 16)) = w;
    }

    const int lane = t & 63;
    const int wave = t >> 6;
    const int wm   = (wave & 1) * 32;
    const int wn   = (wave >> 1) * 64;
    const int lm   = lane & 15;
    const int lq   = lane >> 4;

    for (int rb = g; rb < NRB; rb += 128) {
        f32x4 acc[2][4];
        #pragma unroll
        for (int i = 0; i < 2; ++i)
            #pragma unroll
            for (int j = 0; j < 4; ++j)
                acc[i][j] = (f32x4){0.f, 0.f, 0.f, 0.f};

        ws_rowblock(A, Ws, As[0], As[1], rb * 64, M, acc, t);

        #pragma unroll
        for (int i = 0; i < 2; ++i) {
            int node = rb * 64 + wm + i * 16 + lm;
            if (node >= M) continue;
            #pragma unroll
            for (int j = 0; j < 4; ++j) {
                int col0 = ch * 128 + wn + j * 16 + lq * 4;
                float4 b4 = *(const float4*)(bias + col0);
                float4 o;
                o.x = acc[i][j][0] + b4.x;
                o.y = acc[i][j][1] + b4.y;
                o.z = acc[i][j][2] + b4.z;
                o.w = acc[i][j][3] + b4.w;
                o.x = (o.x >= 0.f) ? o.x : 0.01f * o.x;
                o.y = (o.y >= 0.f) ? o.y : 0.01f * o.y;
                o.z = (o.z >= 0.f) ? o.z : 0.01f * o.z;
                o.w = (o.w >= 0.f) ? o.w : 0.01f * o.w;
                *(float4*)(out + (size_t)node * 256 + col0) = o;
            }
        }
    }
}

// ---------------------------------------------------------------------------
// Dispatch 2: attention, head-sharded (head = blockIdx.x & 7 -> XCD L2 shard).
// kv [8][N][64] in 16B chunks {4 k fp16 | 4 v bf16}; fully-coalesced gathers.
// Direct nbr/wgt loads, no softmax max-pass (|z|<=~1), reduce-scatter dot and
// v-reduction; 23 cross-lane ops per group.
// ---------------------------------------------------------------------------
__global__ __launch_bounds__(256) void attn_shard(
    const unsigned short* __restrict__ qh, const unsigned short* __restrict__ kv,
    const int* __restrict__ nbr, const float* __restrict__ wgt,
    unsigned short* __restrict__ agg)
{
    const int h    = blockIdx.x & 7;
    const int t    = threadIdx.x;
    const int lane = t & 31;
    const int n    = (blockIdx.x >> 3) * 8 + (t >> 5);

    const size_t hkv = (size_t)h * ((size_t)N_NODES * 64);
    const size_t hq  = (size_t)h * ((size_t)N_NODES * 32);

    const int cg = lane & 7;
    const int dg = lane >> 3;            // 0..3

    int nbj[8];
    #pragma unroll
    for (int j = 0; j < 8; ++j)
        nbj[j] = nbr[n * 32 + dg + 4 * j];
    const float wm = wgt[n * 32 + dg + 4 * cg];

    uint4 kvr[8];
    #pragma unroll
    for (int j = 0; j < 8; ++j)
        kvr[j] = *(const uint4*)(kv + hkv + (size_t)nbj[j] * 64 + cg * 8);

    uint2 qc = *(const uint2*)(qh + hq + (size_t)n * 32 + cg * 4);

    float p[8];
    #pragma unroll
    for (int j = 0; j < 8; ++j) {
        float s = __builtin_amdgcn_fdot2(u2h2(kvr[j].x), u2h2(qc.x), 0.f, false);
        p[j]    = __builtin_amdgcn_fdot2(u2h2(kvr[j].y), u2h2(qc.y), s, false);
    }

    // reduce-scatter over cg (xor 4,2,1): lane ends with dot of nbr dg+4*cg
    const bool b4 = (cg & 4) != 0;
    float q4[4];
    #pragma unroll
    for (int jj = 0; jj < 4; ++jj) {
        float snd = b4 ? p[jj] : p[jj + 4];
        float kp  = b4 ? p[jj + 4] : p[jj];
        q4[jj] = kp + swz<SWZ_X4>(snd);
    }
    const bool b2 = (cg & 2) != 0;
    float q2[2];
    #pragma unroll
    for (int jj = 0; jj < 2; ++jj) {
        float snd = b2 ? q4[jj] : q4[jj + 2];
        float kp  = b2 ? q4[jj + 2] : q4[jj];
        q2[jj] = kp + swz<SWZ_X2>(snd);
    }
    const bool b1 = (cg & 1) != 0;
    float sc;
    {
        float snd = b1 ? q2[0] : q2[1];
        float kp  = b1 ? q2[1] : q2[0];
        sc = kp + swz<SWZ_X1>(snd);
    }

    float zl = sc * wm * 0.25500917211914f;          // / sqrt(32) * log2(e)
    float e  = __builtin_amdgcn_exp2f(zl);
    float ssum = e;
    ssum += swz<SWZ_X1>(ssum);
    ssum += swz<SWZ_X2>(ssum);
    ssum += swz<SWZ_X4>(ssum);
    ssum += swz<SWZ_X8>(ssum);
    ssum += swz<SWZ_X16>(ssum);
    const float aw = e * __builtin_amdgcn_rcpf(ssum);

    float a0 = 0.f, a1 = 0.f, a2 = 0.f, a3 = 0.f;
    #pragma unroll
    for (int j = 0; j < 8; ++j) {
        float awv = __shfl(aw, 8 * dg + j, 32);
        a0 = fmaf(awv, bf_lo(kvr[j].z), a0);
        a1 = fmaf(awv, bf_hi(kvr[j].z), a1);
        a2 = fmaf(awv, bf_lo(kvr[j].w), a2);
        a3 = fmaf(awv, bf_hi(kvr[j].w), a3);
    }

    const bool r1 = (dg & 1) != 0;
    float s0 = r1 ? a0 : a1;
    float s1 = r1 ? a2 : a3;
    float k0 = r1 ? a1 : a0;
    float k1 = r1 ? a3 : a2;
    k0 += swz<SWZ_X8>(s0);
    k1 += swz<SWZ_X8>(s1);
    const bool r2 = (dg & 2) != 0;
    float s2v = r2 ? k0 : k1;
    float k2v = r2 ? k1 : k0;
    float r = k2v + swz<SWZ_X16>(s2v);

    agg[(size_t)n * 256 + h * 32 + cg * 4 + dg] = f2bf(r);
}

// ---------------------------------------------------------------------------
extern "C" void kernel_launch(void* const* d_in, const int* in_sizes, int n_in,
                              void* d_out, int out_size, void* d_ws, size_t ws_size,
                              hipStream_t stream)
{
    const float* h   = (const float*)d_in[0];
    const int*   nbr = (const int*)  d_in[1];
    const float* ew  = (const float*)d_in[2];
    const float* Wq  = (const float*)d_in[3];
    const float* bq  = (const float*)d_in[4];
    const float* Wk  = (const float*)d_in[5];
    const float* bk  = (const float*)d_in[6];
    const float* Wv  = (const float*)d_in[7];
    const float* bv  = (const float*)d_in[8];
    const float* Wo  = (const float*)d_in[9];
    const float* bo  = (const float*)d_in[10];
    float* out = (float*)d_out;

    const size_t NM = (size_t)N_NODES * HID;   // 5,120,000
    char* ws = (char*)d_ws;
    unsigned short* qb   = (unsigned short*)ws; ws += NM * 2;   // fp16 [8][N][32]
    unsigned short* kvb  = (unsigned short*)ws; ws += NM * 4;   // [8][N][64] 16B-chunk k|v
    unsigned short* aggb = (unsigned short*)ws; ws += NM * 2;   // bf16 [N][256]
    unsigned short* Wbb  = (unsigned short*)ws; ws += 4 * 65536 * 2; // bf16 Wq|Wk|Wv|Wo
    float* wgt = (float*)ws;                    ws += (size_t)N_NODES * 32 * 4;

    // hb (bf16 h) aliases aggb: gemm_qkv (reads hb) completes before
    // attn_shard (writes aggb) by stream ordering.
    unsigned short* hb = aggb;

    dim3 blk(256);

    prep<<<dim3(5128), blk, 0, stream>>>(h, Wq, Wk, Wv, Wo, ew, hb, Wbb, wgt);

    gemm_qkv<<<dim3(528), blk, 0, stream>>>(hb, Wbb, bq, bk, bv, qb, kvb, N_NODES);

    attn_shard<<<dim3(20000), blk, 0, stream>>>(qb, kvb, nbr, wgt, aggb);

    gemm_out<<<dim3(256), blk, 0, stream>>>(aggb, Wbb + 3 * 65536, bo, out, N_NODES);
}

// Round 3
// 172.698 us; speedup vs baseline: 1.0562x; 1.0562x over previous
//
#include <hip/hip_runtime.h>

#define N_NODES 20000
#define HID     256
#define DEG     32
#define TOPK    16
#define NRB     313      // ceil(20000/64) row-blocks of 64

typedef __attribute__((ext_vector_type(8))) short short8;
typedef __attribute__((ext_vector_type(4))) float f32x4;
typedef __attribute__((ext_vector_type(2))) _Float16 half2_t;

__device__ inline unsigned short f2bf(float f) {
    unsigned u = __float_as_uint(f);
    unsigned r = (u + 0x7FFFu + ((u >> 16) & 1u)) >> 16;  // RNE
    return (unsigned short)r;
}
__device__ inline float bf_lo(unsigned u) { return __uint_as_float(u << 16); }
__device__ inline float bf_hi(unsigned u) { return __uint_as_float(u & 0xFFFF0000u); }

__device__ inline unsigned short f2h(float f) {
    _Float16 h = (_Float16)f;               // v_cvt_f16_f32 (RNE)
    return __builtin_bit_cast(unsigned short, h);
}
__device__ inline half2_t u2h2(unsigned u) { return __builtin_bit_cast(half2_t, u); }

__device__ inline ushort4 cvt4(float4 f) {
    ushort4 o;
    o.x = f2bf(f.x); o.y = f2bf(f.y); o.z = f2bf(f.z); o.w = f2bf(f.w);
    return o;
}

// static xor-lane exchange within 32-lane groups via ds_swizzle (no vaddr).
#define SWZ_X1  0x041F
#define SWZ_X2  0x081F
#define SWZ_X4  0x101F
#define SWZ_X8  0x201F
#define SWZ_X16 0x401F
template<int IMM>
__device__ __forceinline__ float swz(float x) {
    return __uint_as_float((unsigned)__builtin_amdgcn_ds_swizzle(
        (int)__float_as_uint(x), IMM));
}

// ---------------------------------------------------------------------------
// GEMM accumulate core (round-1 structure: 27.6KB LDS -> 5 blocks/CU, 20
// waves/CU; redundant W staging is latency-hidden by occupancy).
// 64x128 tile, BK=64, 256 thr (4 waves), mfma 16x16x32, swapped operands.
// ---------------------------------------------------------------------------
#define PADE 8
__device__ __forceinline__ void gemm_tile64(
    const unsigned short* __restrict__ A, const unsigned short* __restrict__ W,
    int M, int rowbase, int colbase, f32x4 acc[2][4])
{
    __shared__ unsigned short As[64][64 + PADE];
    __shared__ unsigned short Ws[128][64 + PADE];

    const int t    = threadIdx.x;
    const int lane = t & 63;
    const int wave = t >> 6;
    const int wm   = (wave & 1) * 32;
    const int wn   = (wave >> 1) * 64;

    const int lm = lane & 15;
    const int q8 = (lane >> 4) * 8;

    for (int k0 = 0; k0 < 256; k0 += 64) {
        #pragma unroll
        for (int c = 0; c < 2; ++c) {
            int idx = t + 256 * c;
            int row = idx >> 3;
            int col = (idx & 7) * 8;
            int grow = rowbase + row;
            uint4 av = make_uint4(0u, 0u, 0u, 0u);
            if (grow < M) av = *(const uint4*)(A + (size_t)grow * 256 + k0 + col);
            *(uint4*)&As[row][col] = av;
        }
        #pragma unroll
        for (int c = 0; c < 4; ++c) {
            int idx = t + 256 * c;
            int row = idx >> 3;
            int col = (idx & 7) * 8;
            uint4 wv = *(const uint4*)(W + (size_t)(colbase + row) * 256 + k0 + col);
            *(uint4*)&Ws[row][col] = wv;
        }
        __syncthreads();

        #pragma unroll
        for (int kk = 0; kk < 64; kk += 32) {
            short8 af[2], bfr[4];
            #pragma unroll
            for (int i = 0; i < 2; ++i)
                af[i] = *(const short8*)&As[wm + i * 16 + lm][kk + q8];
            #pragma unroll
            for (int j = 0; j < 4; ++j)
                bfr[j] = *(const short8*)&Ws[wn + j * 16 + lm][kk + q8];
            #pragma unroll
            for (int i = 0; i < 2; ++i)
                #pragma unroll
                for (int j = 0; j < 4; ++j)
                    acc[i][j] = __builtin_amdgcn_mfma_f32_16x16x32_bf16(
                        bfr[j], af[i], acc[i][j], 0, 0, 0);   // swapped operands
        }
        __syncthreads();
    }
}

// ---------------------------------------------------------------------------
// Dispatch 0: prep — h fp32->bf16 (once), Wq/Wk/Wv/Wo fp32->bf16 (once, into
// one contiguous Wb buffer), top-16 edge-weight mask + normalize.
// ---------------------------------------------------------------------------
__global__ __launch_bounds__(256) void prep(
    const float* __restrict__ h,
    const float* __restrict__ Wq, const float* __restrict__ Wk,
    const float* __restrict__ Wv, const float* __restrict__ Wo,
    const float* __restrict__ ew,
    unsigned short* __restrict__ hb, unsigned short* __restrict__ Wb,
    float* __restrict__ wgt)
{
    const int id = blockIdx.x;
    const int t  = threadIdx.x;

    if (id < 2500) {                      // ---- h convert ----
        size_t i = ((size_t)id * 256 + t) * 8;
        float4 f0 = *(const float4*)(h + i);
        float4 f1 = *(const float4*)(h + i + 4);
        *(ushort4*)(hb + i)     = cvt4(f0);
        *(ushort4*)(hb + i + 4) = cvt4(f1);
        return;
    }
    if (id < 2628) {                      // ---- W convert ----
        int e = ((id - 2500) * 256 + t) * 8;     // 0..262136
        const float* W = (e < 65536) ? Wq : (e < 131072) ? Wk
                       : (e < 196608) ? Wv : Wo;
        int off = e & 65535;
        float4 f0 = *(const float4*)(W + off);
        float4 f1 = *(const float4*)(W + off + 4);
        *(ushort4*)(Wb + e)     = cvt4(f0);
        *(ushort4*)(Wb + e + 4) = cvt4(f1);
        return;
    }
    // ---- topk ----
    int n = (id - 2628) * 8 + (t >> 5);
    int lane = t & 31;
    float my = ew[n * 32 + lane];
    int cnt = 0;
    #pragma unroll
    for (int j = 0; j < 32; ++j) {
        float o = __shfl(my, j, 32);
        cnt += (o > my || (o == my && j < lane)) ? 1 : 0;
    }
    float w = (cnt < TOPK) ? my : 0.0f;
    float s = w;
    #pragma unroll
    for (int off = 16; off; off >>= 1) s += __shfl_xor(s, off, 32);
    wgt[n * 32 + lane] = w / (s + 1e-5f);
}

// ---------------------------------------------------------------------------
// Dispatch 1: q/k/v projections (round-1 structure). 1920 GEMM blocks,
// XCD-pinned 64-row blocks (id&7), variant=(z,by).
//   q  -> fp16 head-major [8][N][32]
//   kv -> [8][N][64], 16B chunks: chunk c = {k[4c..4c+3] fp16, v[4c..4c+3] bf16}
// ---------------------------------------------------------------------------
__global__ __launch_bounds__(256) void gemm_qkv(
    const unsigned short* __restrict__ A, const unsigned short* __restrict__ Wb,
    const float* __restrict__ bq, const float* __restrict__ bk,
    const float* __restrict__ bv,
    unsigned short* __restrict__ Cq, unsigned short* __restrict__ kvo, int M)
{
    const int id = blockIdx.x;
    const int t  = threadIdx.x;

    const int xcd     = id & 7;
    const int rest    = id >> 3;          // 0..239
    const int rowblk  = xcd + 8 * (rest / 6);
    const int variant = rest % 6;
    if (rowblk >= NRB) return;
    const int z  = variant >> 1;
    const int by = variant & 1;

    const unsigned short* W = Wb + z * 65536;
    const float* bias = (z == 0) ? bq : (z == 1) ? bk : bv;

    f32x4 acc[2][4];
    #pragma unroll
    for (int i = 0; i < 2; ++i)
        #pragma unroll
        for (int j = 0; j < 4; ++j)
            acc[i][j] = (f32x4){0.f, 0.f, 0.f, 0.f};

    gemm_tile64(A, W, M, rowblk * 64, by * 128, acc);

    const int lane = t & 63;
    const int wave = t >> 6;
    const int wm   = (wave & 1) * 32;
    const int wn   = (wave >> 1) * 64;
    const int lm   = lane & 15;
    const int lq   = lane >> 4;

    #pragma unroll
    for (int i = 0; i < 2; ++i) {
        int node = rowblk * 64 + wm + i * 16 + lm;
        if (node >= M) continue;
        #pragma unroll
        for (int j = 0; j < 4; ++j) {
            int col0 = by * 128 + wn + j * 16 + lq * 4;   // 4 consecutive cols
            float4 b4 = *(const float4*)(bias + col0);
            float x0 = acc[i][j][0] + b4.x;
            float x1 = acc[i][j][1] + b4.y;
            float x2 = acc[i][j][2] + b4.z;
            float x3 = acc[i][j][3] + b4.w;
            int hh = col0 >> 5, cc = col0 & 31;
            if (z == 0) {
                ushort4 o; o.x = f2h(x0); o.y = f2h(x1); o.z = f2h(x2); o.w = f2h(x3);
                *(ushort4*)(Cq + (size_t)hh * ((size_t)N_NODES * 32)
                               + (size_t)node * 32 + cc) = o;
            } else if (z == 1) {
                ushort4 o; o.x = f2h(x0); o.y = f2h(x1); o.z = f2h(x2); o.w = f2h(x3);
                *(ushort4*)(kvo + (size_t)hh * ((size_t)N_NODES * 64)
                               + (size_t)node * 64 + (cc >> 2) * 8) = o;
            } else {
                ushort4 o; o.x = f2bf(x0); o.y = f2bf(x1); o.z = f2bf(x2); o.w = f2bf(x3);
                *(ushort4*)(kvo + (size_t)hh * ((size_t)N_NODES * 64)
                               + (size_t)node * 64 + (cc >> 2) * 8 + 4) = o;
            }
        }
    }
}

// ---------------------------------------------------------------------------
// Dispatch 3: o-projection (round-1 structure). fp32 out + fused leaky-relu.
// ---------------------------------------------------------------------------
__global__ __launch_bounds__(256) void gemm_out(
    const unsigned short* __restrict__ A, const unsigned short* __restrict__ W,
    const float* __restrict__ bias, float* __restrict__ out, int M)
{
    const int id     = blockIdx.x;
    const int xcd    = id & 7;
    const int rest   = id >> 3;           // 0..79
    const int rowblk = xcd + 8 * (rest >> 1);
    const int ch     = rest & 1;
    if (rowblk >= NRB) return;

    f32x4 acc[2][4];
    #pragma unroll
    for (int i = 0; i < 2; ++i)
        #pragma unroll
        for (int j = 0; j < 4; ++j)
            acc[i][j] = (f32x4){0.f, 0.f, 0.f, 0.f};

    gemm_tile64(A, W, M, rowblk * 64, ch * 128, acc);

    const int lane = threadIdx.x & 63;
    const int wave = threadIdx.x >> 6;
    const int wm   = (wave & 1) * 32;
    const int wn   = (wave >> 1) * 64;
    const int lm   = lane & 15;
    const int lq   = lane >> 4;

    #pragma unroll
    for (int i = 0; i < 2; ++i) {
        int node = rowblk * 64 + wm + i * 16 + lm;
        if (node >= M) continue;
        #pragma unroll
        for (int j = 0; j < 4; ++j) {
            int col0 = ch * 128 + wn + j * 16 + lq * 4;
            float4 b4 = *(const float4*)(bias + col0);
            float4 o;
            o.x = acc[i][j][0] + b4.x;
            o.y = acc[i][j][1] + b4.y;
            o.z = acc[i][j][2] + b4.z;
            o.w = acc[i][j][3] + b4.w;
            o.x = (o.x >= 0.f) ? o.x : 0.01f * o.x;
            o.y = (o.y >= 0.f) ? o.y : 0.01f * o.y;
            o.z = (o.z >= 0.f) ? o.z : 0.01f * o.z;
            o.w = (o.w >= 0.f) ? o.w : 0.01f * o.w;
            *(float4*)(out + (size_t)node * 256 + col0) = o;
        }
    }
}

// ---------------------------------------------------------------------------
// Dispatch 2: attention, head-sharded. NEW: each 32-lane group processes TWO
// nodes — all 16 uint4 gathers issued up front (2x in-flight bytes/wave to
// cover L2 latency), and the two nodes' serial swizzle-reduce/softmax chains
// interleave (2x ILP on the serial dependency chains).
// Block 256 thr = 8 groups -> 16 nodes/block; grid 1250*8 heads = 10000.
// ---------------------------------------------------------------------------
__global__ __launch_bounds__(256) void attn_shard(
    const unsigned short* __restrict__ qh, const unsigned short* __restrict__ kv,
    const int* __restrict__ nbr, const float* __restrict__ wgt,
    unsigned short* __restrict__ agg)
{
    const int h    = blockIdx.x & 7;
    const int t    = threadIdx.x;
    const int lane = t & 31;
    const int grp  = t >> 5;                       // 0..7
    const int n0   = (blockIdx.x >> 3) * 16 + grp * 2;

    const size_t hkv = (size_t)h * ((size_t)N_NODES * 64);
    const size_t hq  = (size_t)h * ((size_t)N_NODES * 32);

    const int cg = lane & 7;
    const int dg = lane >> 3;                      // 0..3

    // ---- issue ALL loads for both nodes first ----
    int nbj[2][8];
    #pragma unroll
    for (int x = 0; x < 2; ++x)
        #pragma unroll
        for (int j = 0; j < 8; ++j)
            nbj[x][j] = nbr[(n0 + x) * 32 + dg + 4 * j];

    float wm[2];
    uint2 qc[2];
    #pragma unroll
    for (int x = 0; x < 2; ++x) {
        wm[x] = wgt[(n0 + x) * 32 + dg + 4 * cg];
        qc[x] = *(const uint2*)(qh + hq + (size_t)(n0 + x) * 32 + cg * 4);
    }

    uint4 kvr[2][8];
    #pragma unroll
    for (int x = 0; x < 2; ++x)
        #pragma unroll
        for (int j = 0; j < 8; ++j)
            kvr[x][j] = *(const uint4*)(kv + hkv + (size_t)nbj[x][j] * 64 + cg * 8);

    // ---- partial scores ----
    float p[2][8];
    #pragma unroll
    for (int x = 0; x < 2; ++x)
        #pragma unroll
        for (int j = 0; j < 8; ++j) {
            float s = __builtin_amdgcn_fdot2(u2h2(kvr[x][j].x), u2h2(qc[x].x), 0.f, false);
            p[x][j] = __builtin_amdgcn_fdot2(u2h2(kvr[x][j].y), u2h2(qc[x].y), s, false);
        }

    // ---- reduce-scatter over cg (xor 4,2,1), both nodes interleaved ----
    const bool b4 = (cg & 4) != 0;
    float q4[2][4];
    #pragma unroll
    for (int x = 0; x < 2; ++x)
        #pragma unroll
        for (int jj = 0; jj < 4; ++jj) {
            float snd = b4 ? p[x][jj] : p[x][jj + 4];
            float kp  = b4 ? p[x][jj + 4] : p[x][jj];
            q4[x][jj] = kp + swz<SWZ_X4>(snd);
        }
    const bool b2 = (cg & 2) != 0;
    float q2[2][2];
    #pragma unroll
    for (int x = 0; x < 2; ++x)
        #pragma unroll
        for (int jj = 0; jj < 2; ++jj) {
            float snd = b2 ? q4[x][jj] : q4[x][jj + 2];
            float kp  = b2 ? q4[x][jj + 2] : q4[x][jj];
            q2[x][jj] = kp + swz<SWZ_X2>(snd);
        }
    const bool b1 = (cg & 1) != 0;
    float sc[2];
    #pragma unroll
    for (int x = 0; x < 2; ++x) {
        float snd = b1 ? q2[x][0] : q2[x][1];
        float kp  = b1 ? q2[x][1] : q2[x][0];
        sc[x] = kp + swz<SWZ_X1>(snd);
    }

    // ---- softmax (no max-pass; |z|<=~1), both nodes interleaved ----
    float e[2], ssum[2];
    #pragma unroll
    for (int x = 0; x < 2; ++x) {
        float zl = sc[x] * wm[x] * 0.25500917211914f;   // / sqrt(32) * log2(e)
        e[x] = __builtin_amdgcn_exp2f(zl);
        ssum[x] = e[x];
    }
    #pragma unroll
    for (int x = 0; x < 2; ++x) ssum[x] += swz<SWZ_X1>(ssum[x]);
    #pragma unroll
    for (int x = 0; x < 2; ++x) ssum[x] += swz<SWZ_X2>(ssum[x]);
    #pragma unroll
    for (int x = 0; x < 2; ++x) ssum[x] += swz<SWZ_X4>(ssum[x]);
    #pragma unroll
    for (int x = 0; x < 2; ++x) ssum[x] += swz<SWZ_X8>(ssum[x]);
    #pragma unroll
    for (int x = 0; x < 2; ++x) ssum[x] += swz<SWZ_X16>(ssum[x]);

    float aw[2];
    #pragma unroll
    for (int x = 0; x < 2; ++x)
        aw[x] = e[x] * __builtin_amdgcn_rcpf(ssum[x]);

    // ---- v accumulate + reduce-scatter over dg ----
    #pragma unroll
    for (int x = 0; x < 2; ++x) {
        float a0 = 0.f, a1 = 0.f, a2 = 0.f, a3 = 0.f;
        #pragma unroll
        for (int j = 0; j < 8; ++j) {
            float awv = __shfl(aw[x], 8 * dg + j, 32);
            a0 = fmaf(awv, bf_lo(kvr[x][j].z), a0);
            a1 = fmaf(awv, bf_hi(kvr[x][j].z), a1);
            a2 = fmaf(awv, bf_lo(kvr[x][j].w), a2);
            a3 = fmaf(awv, bf_hi(kvr[x][j].w), a3);
        }
        const bool r1 = (dg & 1) != 0;
        float s0 = r1 ? a0 : a1;
        float s1 = r1 ? a2 : a3;
        float k0 = r1 ? a1 : a0;
        float k1 = r1 ? a3 : a2;
        k0 += swz<SWZ_X8>(s0);
        k1 += swz<SWZ_X8>(s1);
        const bool r2 = (dg & 2) != 0;
        float s2v = r2 ? k0 : k1;
        float k2v = r2 ? k1 : k0;
        float r = k2v + swz<SWZ_X16>(s2v);

        agg[(size_t)(n0 + x) * 256 + h * 32 + cg * 4 + dg] = f2bf(r);
    }
}

// ---------------------------------------------------------------------------
extern "C" void kernel_launch(void* const* d_in, const int* in_sizes, int n_in,
                              void* d_out, int out_size, void* d_ws, size_t ws_size,
                              hipStream_t stream)
{
    const float* h   = (const float*)d_in[0];
    const int*   nbr = (const int*)  d_in[1];
    const float* ew  = (const float*)d_in[2];
    const float* Wq  = (const float*)d_in[3];
    const float* bq  = (const float*)d_in[4];
    const float* Wk  = (const float*)d_in[5];
    const float* bk  = (const float*)d_in[6];
    const float* Wv  = (const float*)d_in[7];
    const float* bv  = (const float*)d_in[8];
    const float* Wo  = (const float*)d_in[9];
    const float* bo  = (const float*)d_in[10];
    float* out = (float*)d_out;

    const size_t NM = (size_t)N_NODES * HID;   // 5,120,000
    char* ws = (char*)d_ws;
    unsigned short* qb   = (unsigned short*)ws; ws += NM * 2;   // fp16 [8][N][32]
    unsigned short* kvb  = (unsigned short*)ws; ws += NM * 4;   // [8][N][64] 16B-chunk k|v
    unsigned short* aggb = (unsigned short*)ws; ws += NM * 2;   // bf16 [N][256]
    unsigned short* Wbb  = (unsigned short*)ws; ws += 4 * 65536 * 2; // bf16 Wq|Wk|Wv|Wo
    float* wgt = (float*)ws;                    ws += (size_t)N_NODES * 32 * 4;

    // hb (bf16 h) aliases aggb: gemm_qkv (reads hb) completes before
    // attn_shard (writes aggb) by stream ordering.
    unsigned short* hb = aggb;

    dim3 blk(256);

    prep<<<dim3(5128), blk, 0, stream>>>(h, Wq, Wk, Wv, Wo, ew, hb, Wbb, wgt);

    gemm_qkv<<<dim3(1920), blk, 0, stream>>>(hb, Wbb, bq, bk, bv, qb, kvb, N_NODES);

    attn_shard<<<dim3(10000), blk, 0, stream>>>(qb, kvb, nbr, wgt, aggb);

    gemm_out<<<dim3(640), blk, 0, stream>>>(aggb, Wbb + 3 * 65536, bo, out, N_NODES);
}

// Round 4
// 166.472 us; speedup vs baseline: 1.0957x; 1.0374x over previous
//
#include <hip/hip_runtime.h>

#define N_NODES 20000
#define HID     256
#define DEG     32
#define TOPK    16
#define NRB     313      // ceil(20000/64) row-blocks of 64

typedef __attribute__((ext_vector_type(8))) short short8;
typedef __attribute__((ext_vector_type(4))) float f32x4;
typedef __attribute__((ext_vector_type(2))) _Float16 half2_t;

__device__ inline unsigned short f2bf(float f) {
    unsigned u = __float_as_uint(f);
    unsigned r = (u + 0x7FFFu + ((u >> 16) & 1u)) >> 16;  // RNE
    return (unsigned short)r;
}
__device__ inline float bf_lo(unsigned u) { return __uint_as_float(u << 16); }
__device__ inline float bf_hi(unsigned u) { return __uint_as_float(u & 0xFFFF0000u); }

__device__ inline unsigned short f2h(float f) {
    _Float16 h = (_Float16)f;               // v_cvt_f16_f32 (RNE)
    return __builtin_bit_cast(unsigned short, h);
}
__device__ inline half2_t u2h2(unsigned u) { return __builtin_bit_cast(half2_t, u); }

__device__ inline ushort4 cvt4(float4 f) {
    ushort4 o;
    o.x = f2bf(f.x); o.y = f2bf(f.y); o.z = f2bf(f.z); o.w = f2bf(f.w);
    return o;
}

// static xor-lane exchange within 32-lane groups via ds_swizzle (no vaddr).
#define SWZ_X1  0x041F
#define SWZ_X2  0x081F
#define SWZ_X4  0x101F
#define SWZ_X8  0x201F
#define SWZ_X16 0x401F
template<int IMM>
__device__ __forceinline__ float swz(float x) {
    return __uint_as_float((unsigned)__builtin_amdgcn_ds_swizzle(
        (int)__float_as_uint(x), IMM));
}
// static broadcast: dst lane l <- src lane (l & 0x18) | ORM  (aw of nbr dg*?+j)
// bit-mode imm: (xor=0)<<10 | ORM<<5 | and_mask=0x18
template<int ORM>
__device__ __forceinline__ float swzb(float x) {
    return __uint_as_float((unsigned)__builtin_amdgcn_ds_swizzle(
        (int)__float_as_uint(x), (ORM << 5) | 0x18));
}

// ---------------------------------------------------------------------------
// GEMM accumulate core (round-1 structure: 27.6KB LDS -> 5 blocks/CU, 20
// waves/CU; redundant W staging is latency-hidden by occupancy).
// 64x128 tile, BK=64, 256 thr (4 waves), mfma 16x16x32, swapped operands.
// ---------------------------------------------------------------------------
#define PADE 8
__device__ __forceinline__ void gemm_tile64(
    const unsigned short* __restrict__ A, const unsigned short* __restrict__ W,
    int M, int rowbase, int colbase, f32x4 acc[2][4])
{
    __shared__ unsigned short As[64][64 + PADE];
    __shared__ unsigned short Ws[128][64 + PADE];

    const int t    = threadIdx.x;
    const int lane = t & 63;
    const int wave = t >> 6;
    const int wm   = (wave & 1) * 32;
    const int wn   = (wave >> 1) * 64;

    const int lm = lane & 15;
    const int q8 = (lane >> 4) * 8;

    for (int k0 = 0; k0 < 256; k0 += 64) {
        #pragma unroll
        for (int c = 0; c < 2; ++c) {
            int idx = t + 256 * c;
            int row = idx >> 3;
            int col = (idx & 7) * 8;
            int grow = rowbase + row;
            uint4 av = make_uint4(0u, 0u, 0u, 0u);
            if (grow < M) av = *(const uint4*)(A + (size_t)grow * 256 + k0 + col);
            *(uint4*)&As[row][col] = av;
        }
        #pragma unroll
        for (int c = 0; c < 4; ++c) {
            int idx = t + 256 * c;
            int row = idx >> 3;
            int col = (idx & 7) * 8;
            uint4 wv = *(const uint4*)(W + (size_t)(colbase + row) * 256 + k0 + col);
            *(uint4*)&Ws[row][col] = wv;
        }
        __syncthreads();

        #pragma unroll
        for (int kk = 0; kk < 64; kk += 32) {
            short8 af[2], bfr[4];
            #pragma unroll
            for (int i = 0; i < 2; ++i)
                af[i] = *(const short8*)&As[wm + i * 16 + lm][kk + q8];
            #pragma unroll
            for (int j = 0; j < 4; ++j)
                bfr[j] = *(const short8*)&Ws[wn + j * 16 + lm][kk + q8];
            #pragma unroll
            for (int i = 0; i < 2; ++i)
                #pragma unroll
                for (int j = 0; j < 4; ++j)
                    acc[i][j] = __builtin_amdgcn_mfma_f32_16x16x32_bf16(
                        bfr[j], af[i], acc[i][j], 0, 0, 0);   // swapped operands
        }
        __syncthreads();
    }
}

// ---------------------------------------------------------------------------
// Dispatch 0: prep — h fp32->bf16 (once), Wq/Wk/Wv/Wo fp32->bf16 (once, into
// one contiguous Wb buffer), top-16 edge-weight mask + normalize.
// ---------------------------------------------------------------------------
__global__ __launch_bounds__(256) void prep(
    const float* __restrict__ h,
    const float* __restrict__ Wq, const float* __restrict__ Wk,
    const float* __restrict__ Wv, const float* __restrict__ Wo,
    const float* __restrict__ ew,
    unsigned short* __restrict__ hb, unsigned short* __restrict__ Wb,
    float* __restrict__ wgt)
{
    const int id = blockIdx.x;
    const int t  = threadIdx.x;

    if (id < 2500) {                      // ---- h convert ----
        size_t i = ((size_t)id * 256 + t) * 8;
        float4 f0 = *(const float4*)(h + i);
        float4 f1 = *(const float4*)(h + i + 4);
        *(ushort4*)(hb + i)     = cvt4(f0);
        *(ushort4*)(hb + i + 4) = cvt4(f1);
        return;
    }
    if (id < 2628) {                      // ---- W convert ----
        int e = ((id - 2500) * 256 + t) * 8;     // 0..262136
        const float* W = (e < 65536) ? Wq : (e < 131072) ? Wk
                       : (e < 196608) ? Wv : Wo;
        int off = e & 65535;
        float4 f0 = *(const float4*)(W + off);
        float4 f1 = *(const float4*)(W + off + 4);
        *(ushort4*)(Wb + e)     = cvt4(f0);
        *(ushort4*)(Wb + e + 4) = cvt4(f1);
        return;
    }
    // ---- topk ----
    int n = (id - 2628) * 8 + (t >> 5);
    int lane = t & 31;
    float my = ew[n * 32 + lane];
    int cnt = 0;
    #pragma unroll
    for (int j = 0; j < 32; ++j) {
        float o = __shfl(my, j, 32);
        cnt += (o > my || (o == my && j < lane)) ? 1 : 0;
    }
    float w = (cnt < TOPK) ? my : 0.0f;
    float s = w;
    #pragma unroll
    for (int off = 16; off; off >>= 1) s += __shfl_xor(s, off, 32);
    wgt[n * 32 + lane] = w / (s + 1e-5f);
}

// ---------------------------------------------------------------------------
// Dispatch 1: q/k/v projections (round-1 structure). 1920 GEMM blocks,
// XCD-pinned 64-row blocks (id&7), variant=(z,by).
//   q  -> fp16 head-major [8][N][32]
//   kv -> [8][N][64], 16B chunks: chunk c = {k[4c..4c+3] fp16, v[4c..4c+3] bf16}
// ---------------------------------------------------------------------------
__global__ __launch_bounds__(256) void gemm_qkv(
    const unsigned short* __restrict__ A, const unsigned short* __restrict__ Wb,
    const float* __restrict__ bq, const float* __restrict__ bk,
    const float* __restrict__ bv,
    unsigned short* __restrict__ Cq, unsigned short* __restrict__ kvo, int M)
{
    const int id = blockIdx.x;
    const int t  = threadIdx.x;

    const int xcd     = id & 7;
    const int rest    = id >> 3;          // 0..239
    const int rowblk  = xcd + 8 * (rest / 6);
    const int variant = rest % 6;
    if (rowblk >= NRB) return;
    const int z  = variant >> 1;
    const int by = variant & 1;

    const unsigned short* W = Wb + z * 65536;
    const float* bias = (z == 0) ? bq : (z == 1) ? bk : bv;

    f32x4 acc[2][4];
    #pragma unroll
    for (int i = 0; i < 2; ++i)
        #pragma unroll
        for (int j = 0; j < 4; ++j)
            acc[i][j] = (f32x4){0.f, 0.f, 0.f, 0.f};

    gemm_tile64(A, W, M, rowblk * 64, by * 128, acc);

    const int lane = t & 63;
    const int wave = t >> 6;
    const int wm   = (wave & 1) * 32;
    const int wn   = (wave >> 1) * 64;
    const int lm   = lane & 15;
    const int lq   = lane >> 4;

    #pragma unroll
    for (int i = 0; i < 2; ++i) {
        int node = rowblk * 64 + wm + i * 16 + lm;
        if (node >= M) continue;
        #pragma unroll
        for (int j = 0; j < 4; ++j) {
            int col0 = by * 128 + wn + j * 16 + lq * 4;   // 4 consecutive cols
            float4 b4 = *(const float4*)(bias + col0);
            float x0 = acc[i][j][0] + b4.x;
            float x1 = acc[i][j][1] + b4.y;
            float x2 = acc[i][j][2] + b4.z;
            float x3 = acc[i][j][3] + b4.w;
            int hh = col0 >> 5, cc = col0 & 31;
            if (z == 0) {
                ushort4 o; o.x = f2h(x0); o.y = f2h(x1); o.z = f2h(x2); o.w = f2h(x3);
                *(ushort4*)(Cq + (size_t)hh * ((size_t)N_NODES * 32)
                               + (size_t)node * 32 + cc) = o;
            } else if (z == 1) {
                ushort4 o; o.x = f2h(x0); o.y = f2h(x1); o.z = f2h(x2); o.w = f2h(x3);
                *(ushort4*)(kvo + (size_t)hh * ((size_t)N_NODES * 64)
                               + (size_t)node * 64 + (cc >> 2) * 8) = o;
            } else {
                ushort4 o; o.x = f2bf(x0); o.y = f2bf(x1); o.z = f2bf(x2); o.w = f2bf(x3);
                *(ushort4*)(kvo + (size_t)hh * ((size_t)N_NODES * 64)
                               + (size_t)node * 64 + (cc >> 2) * 8 + 4) = o;
            }
        }
    }
}

// ---------------------------------------------------------------------------
// Dispatch 3: o-projection (round-1 structure). fp32 out + fused leaky-relu.
// ---------------------------------------------------------------------------
__global__ __launch_bounds__(256) void gemm_out(
    const unsigned short* __restrict__ A, const unsigned short* __restrict__ W,
    const float* __restrict__ bias, float* __restrict__ out, int M)
{
    const int id     = blockIdx.x;
    const int xcd    = id & 7;
    const int rest   = id >> 3;           // 0..79
    const int rowblk = xcd + 8 * (rest >> 1);
    const int ch     = rest & 1;
    if (rowblk >= NRB) return;

    f32x4 acc[2][4];
    #pragma unroll
    for (int i = 0; i < 2; ++i)
        #pragma unroll
        for (int j = 0; j < 4; ++j)
            acc[i][j] = (f32x4){0.f, 0.f, 0.f, 0.f};

    gemm_tile64(A, W, M, rowblk * 64, ch * 128, acc);

    const int lane = threadIdx.x & 63;
    const int wave = threadIdx.x >> 6;
    const int wm   = (wave & 1) * 32;
    const int wn   = (wave >> 1) * 64;
    const int lm   = lane & 15;
    const int lq   = lane >> 4;

    #pragma unroll
    for (int i = 0; i < 2; ++i) {
        int node = rowblk * 64 + wm + i * 16 + lm;
        if (node >= M) continue;
        #pragma unroll
        for (int j = 0; j < 4; ++j) {
            int col0 = ch * 128 + wn + j * 16 + lq * 4;
            float4 b4 = *(const float4*)(bias + col0);
            float4 o;
            o.x = acc[i][j][0] + b4.x;
            o.y = acc[i][j][1] + b4.y;
            o.z = acc[i][j][2] + b4.z;
            o.w = acc[i][j][3] + b4.w;
            o.x = (o.x >= 0.f) ? o.x : 0.01f * o.x;
            o.y = (o.y >= 0.f) ? o.y : 0.01f * o.y;
            o.z = (o.z >= 0.f) ? o.z : 0.01f * o.z;
            o.w = (o.w >= 0.f) ? o.w : 0.01f * o.w;
            *(float4*)(out + (size_t)node * 256 + col0) = o;
        }
    }
}

// ---------------------------------------------------------------------------
// Dispatch 2: attention, head-sharded (head = blockIdx.x & 7 -> XCD L2 shard).
// Round-1 single-node structure (TLP > per-wave ILP: round-3's 2-node version
// halved occupancy and regressed). This rev: aw broadcast via STATIC
// ds_swizzle (src = (lane&0x18)|j) instead of __shfl/ds_bpermute — removes
// 8 vaddr computations (~16-24 VALU) + frees regs on the tail.
// ---------------------------------------------------------------------------
__global__ __launch_bounds__(256) void attn_shard(
    const unsigned short* __restrict__ qh, const unsigned short* __restrict__ kv,
    const int* __restrict__ nbr, const float* __restrict__ wgt,
    unsigned short* __restrict__ agg)
{
    const int h    = blockIdx.x & 7;
    const int t    = threadIdx.x;
    const int lane = t & 31;
    const int n    = (blockIdx.x >> 3) * 8 + (t >> 5);

    const size_t hkv = (size_t)h * ((size_t)N_NODES * 64);
    const size_t hq  = (size_t)h * ((size_t)N_NODES * 32);

    const int cg = lane & 7;
    const int dg = lane >> 3;            // 0..3

    // neighbors this lane gathers: dg + 4j, j = 0..7 — direct coalesced loads
    int nbj[8];
    #pragma unroll
    for (int j = 0; j < 8; ++j)
        nbj[j] = nbr[n * 32 + dg + 4 * j];
    // edge weight of the neighbor this lane will score (m = dg + 4*cg)
    const float wm = wgt[n * 32 + dg + 4 * cg];

    // one fully-coalesced uint4 per neighbor: chunk cg = 4 k fp16 + 4 v bf16
    uint4 kvr[8];
    #pragma unroll
    for (int j = 0; j < 8; ++j)
        kvr[j] = *(const uint4*)(kv + hkv + (size_t)nbj[j] * 64 + cg * 8);

    // q chunk: 4 fp16 at cols 4cg..4cg+3 (broadcast across dg)
    uint2 qc = *(const uint2*)(qh + hq + (size_t)n * 32 + cg * 4);

    // partial scores (this lane's 4 cols) for its 8 neighbors
    float p[8];
    #pragma unroll
    for (int j = 0; j < 8; ++j) {
        float s = __builtin_amdgcn_fdot2(u2h2(kvr[j].x), u2h2(qc.x), 0.f, false);
        p[j]    = __builtin_amdgcn_fdot2(u2h2(kvr[j].y), u2h2(qc.y), s, false);
    }

    // reduce-scatter over cg (xor 4,2,1): lane ends with dot of nbr dg+4*cg
    const bool b4 = (cg & 4) != 0;
    float q4[4];
    #pragma unroll
    for (int jj = 0; jj < 4; ++jj) {
        float snd = b4 ? p[jj] : p[jj + 4];
        float kp  = b4 ? p[jj + 4] : p[jj];
        q4[jj] = kp + swz<SWZ_X4>(snd);
    }
    const bool b2 = (cg & 2) != 0;
    float q2[2];
    #pragma unroll
    for (int jj = 0; jj < 2; ++jj) {
        float snd = b2 ? q4[jj] : q4[jj + 2];
        float kp  = b2 ? q4[jj + 2] : q4[jj];
        q2[jj] = kp + swz<SWZ_X2>(snd);
    }
    const bool b1 = (cg & 1) != 0;
    float sc;
    {
        float snd = b1 ? q2[0] : q2[1];
        float kp  = b1 ? q2[1] : q2[0];
        sc = kp + swz<SWZ_X1>(snd);
    }

    // logit in exp2 domain; NO max-subtraction: |z| <= ~1 (w<=1, |sc| small),
    // softmax is shift-invariant so result is mathematically identical.
    float zl = sc * wm * 0.25500917211914f;          // / sqrt(32) * log2(e)
    float e  = __builtin_amdgcn_exp2f(zl);
    float ssum = e;
    ssum += swz<SWZ_X1>(ssum);
    ssum += swz<SWZ_X2>(ssum);
    ssum += swz<SWZ_X4>(ssum);
    ssum += swz<SWZ_X8>(ssum);
    ssum += swz<SWZ_X16>(ssum);
    const float aw = e * __builtin_amdgcn_rcpf(ssum);   // attn weight of nbr dg+4cg

    // v accumulate: cols 4cg..4cg+3; aw of neighbor dg+4j lives at lane 8*dg+j
    // = (lane & 0x18) | j  ->  static ds_swizzle broadcast, no vaddr.
    float a0 = 0.f, a1 = 0.f, a2 = 0.f, a3 = 0.f;
#define VACC(J) { float awv = swzb<J>(aw); \
        a0 = fmaf(awv, bf_lo(kvr[J].z), a0); \
        a1 = fmaf(awv, bf_hi(kvr[J].z), a1); \
        a2 = fmaf(awv, bf_lo(kvr[J].w), a2); \
        a3 = fmaf(awv, bf_hi(kvr[J].w), a3); }
    VACC(0) VACC(1) VACC(2) VACC(3) VACC(4) VACC(5) VACC(6) VACC(7)
#undef VACC

    // reduce-scatter over dg (xor8 then xor16): lane ends with component dg
    // of chunk cg, fully summed over all 4 dg partials.
    const bool r1 = (dg & 1) != 0;
    float s0 = r1 ? a0 : a1;
    float s1 = r1 ? a2 : a3;
    float k0 = r1 ? a1 : a0;
    float k1 = r1 ? a3 : a2;
    k0 += swz<SWZ_X8>(s0);
    k1 += swz<SWZ_X8>(s1);
    const bool r2 = (dg & 2) != 0;
    float s2v = r2 ? k0 : k1;
    float k2v = r2 ? k1 : k0;
    float r = k2v + swz<SWZ_X16>(s2v);

    agg[(size_t)n * 256 + h * 32 + cg * 4 + dg] = f2bf(r);
}

// ---------------------------------------------------------------------------
extern "C" void kernel_launch(void* const* d_in, const int* in_sizes, int n_in,
                              void* d_out, int out_size, void* d_ws, size_t ws_size,
                              hipStream_t stream)
{
    const float* h   = (const float*)d_in[0];
    const int*   nbr = (const int*)  d_in[1];
    const float* ew  = (const float*)d_in[2];
    const float* Wq  = (const float*)d_in[3];
    const float* bq  = (const float*)d_in[4];
    const float* Wk  = (const float*)d_in[5];
    const float* bk  = (const float*)d_in[6];
    const float* Wv  = (const float*)d_in[7];
    const float* bv  = (const float*)d_in[8];
    const float* Wo  = (const float*)d_in[9];
    const float* bo  = (const float*)d_in[10];
    float* out = (float*)d_out;

    const size_t NM = (size_t)N_NODES * HID;   // 5,120,000
    char* ws = (char*)d_ws;
    unsigned short* qb   = (unsigned short*)ws; ws += NM * 2;   // fp16 [8][N][32]
    unsigned short* kvb  = (unsigned short*)ws; ws += NM * 4;   // [8][N][64] 16B-chunk k|v
    unsigned short* aggb = (unsigned short*)ws; ws += NM * 2;   // bf16 [N][256]
    unsigned short* Wbb  = (unsigned short*)ws; ws += 4 * 65536 * 2; // bf16 Wq|Wk|Wv|Wo
    float* wgt = (float*)ws;                    ws += (size_t)N_NODES * 32 * 4;

    // hb (bf16 h) aliases aggb: gemm_qkv (reads hb) completes before
    // attn_shard (writes aggb) by stream ordering.
    unsigned short* hb = aggb;

    dim3 blk(256);

    prep<<<dim3(5128), blk, 0, stream>>>(h, Wq, Wk, Wv, Wo, ew, hb, Wbb, wgt);

    gemm_qkv<<<dim3(1920), blk, 0, stream>>>(hb, Wbb, bq, bk, bv, qb, kvb, N_NODES);

    attn_shard<<<dim3(20000), blk, 0, stream>>>(qb, kvb, nbr, wgt, aggb);

    gemm_out<<<dim3(640), blk, 0, stream>>>(aggb, Wbb + 3 * 65536, bo, out, N_NODES);
}